// Round 10
// baseline (465.949 us; speedup 1.0000x reference)
//
#include <hip/hip_runtime.h>
#include <hip/hip_cooperative_groups.h>

namespace cg = cooperative_groups;

#define NUM_NETS     100000
#define PINS_PER_NET 5
#define NUM_PINS     (NUM_NETS * PINS_PER_NET)
#define NB           512
#define BIN_H        1.953125f          /* 1000/512, exact in fp32 */
#define INV_H        0.512f             /* 512/1000 */
#define OUT_SCALE    (1.0f / 195.3125f) /* 1/(BIN_SIZE_X * 100 tracks) */

#define SW           8                  /* stripe width (x bins) */
#define NSTRIPES     (NB / SW)          /* 64 */
#define NSLICE       8                  /* y slices */
#define SLH          (NB / NSLICE)      /* 64 */
#define NBUCKET      (NSTRIPES * NSLICE)/* 512 */
#define ITEMS_MAX    1048576
#define STRIPE       8
#define NSTRIPE      (NB / STRIPE)      /* 64 */
#define GBLK         512                /* cooperative grid blocks */
#define TPB          256
#define NBLK         ((NUM_NETS + 1023) / 1024)  /* fallback path */

// bucket id for cluster cell (kx,ky): stripe kx>>3, slice ky>>6
template <class F>
__device__ __forceinline__ void for_each_bucket(int kx, int ky, F&& f) {
    int s0 = kx >> 3, t0 = ky >> 6;
    int s1 = (kx + 1 < NB && ((kx + 1) >> 3) != s0) ? ((kx + 1) >> 3) : -1;
    int t1 = (ky + 1 < NB && ((ky + 1) >> 6) != t0) ? ((ky + 1) >> 6) : -1;
    f(s0 * NSLICE + t0);
    if (s1 >= 0)            f(s1 * NSLICE + t0);
    if (t1 >= 0)            f(s0 * NSLICE + t1);
    if (s1 >= 0 && t1 >= 0) f(s1 * NSLICE + t1);
}

// ---------------------------------------------------------------------------
// Fused cooperative kernel: all 8 phases, grid.sync() between them.
// ---------------------------------------------------------------------------
__global__ void __launch_bounds__(TPB) fused_kernel(
        const float* __restrict__ pin_pos,
        const int*   __restrict__ flat_netpin,
        const float* __restrict__ net_weights,
        float4* __restrict__ recA, float4* __restrict__ recB,
        int* __restrict__ pcnt, int* __restrict__ gcnt,
        int* __restrict__ goff, int* __restrict__ gcur,
        float4* __restrict__ items,
        float* __restrict__ Uh, float* __restrict__ Uv,
        float* __restrict__ Th, float* __restrict__ Tv,
        float* __restrict__ out) {
    cg::grid_group grid = cg::this_grid();
    __shared__ int shm_i[1024];                 /* 4 KB, aliased per phase */
    float* shm_f = (float*)shm_i;
    int tid = threadIdx.x;
    int bid = blockIdx.x;
    int n   = bid * TPB + tid;                  /* one net per thread */

    /* ---- P1: bbox + per-block bucket counts ---- */
    {
        int* lcnt = shm_i;
        for (int k = tid; k < NBUCKET; k += TPB) lcnt[k] = 0;
        __syncthreads();
        if (n < NUM_NETS) {
            float xmn = 1e30f, xmx = -1e30f, ymn = 1e30f, ymx = -1e30f;
#pragma unroll
            for (int p = 0; p < PINS_PER_NET; ++p) {
                int pi  = flat_netpin[n * PINS_PER_NET + p];
                float x = pin_pos[pi];
                float y = pin_pos[NUM_PINS + pi];
                xmn = fminf(xmn, x); xmx = fmaxf(xmx, x);
                ymn = fminf(ymn, y); ymx = fmaxf(ymx, y);
            }
            float w = net_weights[n];
            int kx1 = min(NB - 1, (int)(xmn * INV_H));
            int kx2 = min(NB - 1, (int)(xmx * INV_H));
            int ky1 = min(NB - 1, (int)(ymn * INV_H));
            int ky2 = min(NB - 1, (int)(ymx * INV_H));
            recA[n] = make_float4(xmn, xmx, ymn, ymx);
            recB[n] = make_float4(w / (ymx - ymn), w / (xmx - xmn),
                                  __uint_as_float((unsigned)kx1 | ((unsigned)kx2 << 16)),
                                  __uint_as_float((unsigned)ky1 | ((unsigned)ky2 << 16)));
#pragma unroll
            for (int cx = 0; cx < 2; ++cx) {
                int kx = cx ? kx2 : kx1;
#pragma unroll
                for (int cy = 0; cy < 2; ++cy) {
                    int ky = cy ? ky2 : ky1;
                    for_each_bucket(kx, ky, [&](int b) { atomicAdd(&lcnt[b], 1); });
                }
            }
        }
        __syncthreads();
        for (int k = tid; k < NBUCKET; k += TPB) pcnt[bid * NBUCKET + k] = lcnt[k];
    }
    grid.sync();

    /* ---- P2: gcnt[bid] = sum of pcnt[*][bid] ---- */
    {
        int s = 0;
        for (int j = tid; j < GBLK; j += TPB) s += pcnt[j * NBUCKET + bid];
#pragma unroll
        for (int o = 1; o < 64; o <<= 1) s += __shfl_xor(s, o);
        int lane = tid & 63, wid = tid >> 6;
        if (lane == 0) shm_i[wid] = s;
        __syncthreads();
        if (tid == 0) gcnt[bid] = shm_i[0] + shm_i[1] + shm_i[2] + shm_i[3];
    }
    grid.sync();

    /* ---- P3: exclusive scan of gcnt -> goff, gcur (block 0) ---- */
    if (bid == 0) {
        int a = gcnt[2 * tid], b = gcnt[2 * tid + 1];
        int s = a + b;
        int lane = tid & 63, wid = tid >> 6;
        int inc = s;
#pragma unroll
        for (int o = 1; o < 64; o <<= 1) {
            int t2 = __shfl_up(inc, o);
            if (lane >= o) inc += t2;
        }
        if (lane == 63) shm_i[wid] = inc;
        __syncthreads();
        int off = 0;
        for (int j = 0; j < wid; ++j) off += shm_i[j];
        int excl = off + inc - s;
        goff[2 * tid] = excl;       gcur[2 * tid] = excl;
        goff[2 * tid + 1] = excl + a; gcur[2 * tid + 1] = excl + a;
    }
    grid.sync();

    /* ---- P4: emit items into exact per-bucket segments ---- */
    {
        int* lc = shm_i;            /* [512] */
        int* lb = shm_i + NBUCKET;  /* [512] */
        for (int k = tid; k < NBUCKET; k += TPB) lc[k] = 0;
        __syncthreads();
        float4 ra, rb;
        int kx1 = 0, kx2 = 0, ky1 = 0, ky2 = 0;
        bool valid = n < NUM_NETS;
        if (valid) {
            ra = recA[n]; rb = recB[n];
            unsigned pkx = __float_as_uint(rb.z), pky = __float_as_uint(rb.w);
            kx1 = (int)(pkx & 0xffffu); kx2 = (int)(pkx >> 16);
            ky1 = (int)(pky & 0xffffu); ky2 = (int)(pky >> 16);
#pragma unroll
            for (int cx = 0; cx < 2; ++cx) {
                int kx = cx ? kx2 : kx1;
#pragma unroll
                for (int cy = 0; cy < 2; ++cy) {
                    int ky = cy ? ky2 : ky1;
                    for_each_bucket(kx, ky, [&](int b) { atomicAdd(&lc[b], 1); });
                }
            }
        }
        __syncthreads();
        for (int k = tid; k < NBUCKET; k += TPB) {
            lb[k] = atomicAdd(&gcur[k], lc[k]);
            lc[k] = 0;
        }
        __syncthreads();
        if (valid) {
            float xmn = ra.x, xmx = ra.y, ymn = ra.z, ymx = ra.w;
            float wh = rb.x, wv = rb.y;
#pragma unroll
            for (int cx = 0; cx < 2; ++cx) {
                int   kx = cx ? kx2 : kx1;
                float xc = cx ? xmx : xmn;
#pragma unroll
                for (int cy = 0; cy < 2; ++cy) {
                    int   ky = cy ? ky2 : ky1;
                    float yc = cy ? ymx : ymn;
                    float sg = (cx ^ cy) ? -1.0f : 1.0f;
                    float4 item = make_float4(xc, yc, sg * wh, sg * wv);
                    for_each_bucket(kx, ky, [&](int b) {
                        int rank = atomicAdd(&lc[b], 1);
                        int pos  = lb[b] + rank;
                        if (pos < ITEMS_MAX) items[pos] = item;
                    });
                }
            }
        }
    }
    grid.sync();

    /* ---- P5: per-bucket accumulate (bucket = bid) ---- */
    {
        float* accH = shm_f;
        float* accV = shm_f + SW * SLH;
        for (int k = tid; k < SW * SLH; k += TPB) { accH[k] = 0.f; accV[k] = 0.f; }
        __syncthreads();
        int st = bid >> 3, sl = bid & 7;
        int x0 = st * SW, y0 = sl * SLH;
        int i0  = goff[bid];
        int cnt = min(gcnt[bid], ITEMS_MAX - i0);
        int end = i0 + cnt;
        for (int q = i0 + tid; q < end; q += TPB) {
            float4 it = items[q];
            int kx = min(NB - 1, (int)(it.x * INV_H));
            int ky = min(NB - 1, (int)(it.y * INV_H));
            float dx0 = (kx + 1) * BIN_H - it.x;
            float dx1 = it.x - kx * BIN_H;
            float dy0 = (ky + 1) * BIN_H - it.y;
            float dy1 = it.y - ky * BIN_H;
            int gy = ky - y0;
            bool ok0 = (unsigned)gy < (unsigned)SLH;
            bool ok1 = ((unsigned)(gy + 1) < (unsigned)SLH) && (ky + 1 < NB);
            int c = kx - x0;
#pragma unroll
            for (int cc = 0; cc < 2; ++cc) {
                int col = c + cc;
                if ((unsigned)col < SW) {
                    float dx = cc ? dx1 : dx0;
                    if (ok0) {
                        int i = col * SLH + gy;
                        atomicAdd(&accH[i], it.z * dx * dy0);
                        atomicAdd(&accV[i], it.w * dx * dy0);
                    }
                    if (ok1) {
                        int i = col * SLH + gy + 1;
                        atomicAdd(&accH[i], it.z * dx * dy1);
                        atomicAdd(&accV[i], it.w * dx * dy1);
                    }
                }
            }
        }
        __syncthreads();
        for (int k = tid; k < SW * SLH; k += TPB) {
            int col = k >> 6, y = k & (SLH - 1);
            int gi = (x0 + col) * NB + y0 + y;
            Uh[gi] = accH[k];
            Uv[gi] = accV[k];
        }
    }
    grid.sync();

    /* ---- P6: inclusive y-scan of row x = bid (pair per thread) ---- */
    {
        int x = bid;
        int lane = tid & 63, wid = tid >> 6;
        /* H */
        {
            float a = Uh[x * NB + 2 * tid], b = Uh[x * NB + 2 * tid + 1];
            float s = a + b, inc = s;
#pragma unroll
            for (int o = 1; o < 64; o <<= 1) {
                float t2 = __shfl_up(inc, o);
                if (lane >= o) inc += t2;
            }
            if (lane == 63) shm_f[wid] = inc;
            __syncthreads();
            float off = 0.f;
            for (int j = 0; j < wid; ++j) off += shm_f[j];
            float tot = off + inc;
            Uh[x * NB + 2 * tid] = tot - b;
            Uh[x * NB + 2 * tid + 1] = tot;
            __syncthreads();
        }
        /* V */
        {
            float a = Uv[x * NB + 2 * tid], b = Uv[x * NB + 2 * tid + 1];
            float s = a + b, inc = s;
#pragma unroll
            for (int o = 1; o < 64; o <<= 1) {
                float t2 = __shfl_up(inc, o);
                if (lane >= o) inc += t2;
            }
            if (lane == 63) shm_f[wid] = inc;
            __syncthreads();
            float off = 0.f;
            for (int j = 0; j < wid; ++j) off += shm_f[j];
            float tot = off + inc;
            Uv[x * NB + 2 * tid] = tot - b;
            Uv[x * NB + 2 * tid + 1] = tot;
        }
    }
    grid.sync();

    /* ---- P7: per-stripe partial column scans + totals (128 blocks) ---- */
    if (bid < 2 * NSTRIPE) {
        int s = bid >> 1;
        int col = (bid & 1) * TPB + tid;
        float h = 0.f, v = 0.f;
#pragma unroll
        for (int i = 0; i < STRIPE; ++i) {
            int row = s * STRIPE + i;
            h += Uh[row * NB + col];  Uh[row * NB + col] = h;
            v += Uv[row * NB + col];  Uv[row * NB + col] = v;
        }
        Th[s * NB + col] = h;
        Tv[s * NB + col] = v;
    }
    grid.sync();

    /* ---- P8: stripe offsets + fused epilogue (128 blocks) ---- */
    if (bid < 2 * NSTRIPE) {
        int s = bid >> 1;
        int col = (bid & 1) * TPB + tid;
        float offh = 0.f, offv = 0.f;
        for (int s2 = 0; s2 < s; ++s2) {
            offh += Th[s2 * NB + col];
            offv += Tv[s2 * NB + col];
        }
#pragma unroll
        for (int i = 0; i < STRIPE; ++i) {
            int row = s * STRIPE + i;
            float h = fabsf(Uh[row * NB + col] + offh) * OUT_SCALE;
            float v = fabsf(Uv[row * NB + col] + offv) * OUT_SCALE;
            float m = fmaxf(h, v);
            out[row * NB + col] = fminf(fmaxf(m * m, 0.5f), 2.0f);
        }
    }
}

// ===========================================================================
// Fallback multi-kernel path (proven R9 pipeline), used if cooperative launch
// is unavailable or workspace is too small.
// ===========================================================================
__global__ __launch_bounds__(1024) void bbox_count_kernel(
        const float* __restrict__ pin_pos,
        const int*   __restrict__ flat_netpin,
        const float* __restrict__ net_weights,
        float4* __restrict__ recA, float4* __restrict__ recB,
        int* __restrict__ pcount) {
    __shared__ int lcnt[NBUCKET];
    int tid = threadIdx.x;
    if (tid < NBUCKET) lcnt[tid] = 0;
    __syncthreads();
    int n = blockIdx.x * 1024 + tid;
    if (n < NUM_NETS) {
        float xmn = 1e30f, xmx = -1e30f, ymn = 1e30f, ymx = -1e30f;
#pragma unroll
        for (int p = 0; p < PINS_PER_NET; ++p) {
            int pi  = flat_netpin[n * PINS_PER_NET + p];
            float x = pin_pos[pi];
            float y = pin_pos[NUM_PINS + pi];
            xmn = fminf(xmn, x); xmx = fmaxf(xmx, x);
            ymn = fminf(ymn, y); ymx = fmaxf(ymx, y);
        }
        float w = net_weights[n];
        int kx1 = min(NB - 1, (int)(xmn * INV_H));
        int kx2 = min(NB - 1, (int)(xmx * INV_H));
        int ky1 = min(NB - 1, (int)(ymn * INV_H));
        int ky2 = min(NB - 1, (int)(ymx * INV_H));
        recA[n] = make_float4(xmn, xmx, ymn, ymx);
        recB[n] = make_float4(w / (ymx - ymn), w / (xmx - xmn),
                              __uint_as_float((unsigned)kx1 | ((unsigned)kx2 << 16)),
                              __uint_as_float((unsigned)ky1 | ((unsigned)ky2 << 16)));
#pragma unroll
        for (int cx = 0; cx < 2; ++cx) {
            int kx = cx ? kx2 : kx1;
#pragma unroll
            for (int cy = 0; cy < 2; ++cy) {
                int ky = cy ? ky2 : ky1;
                for_each_bucket(kx, ky, [&](int b) { atomicAdd(&lcnt[b], 1); });
            }
        }
    }
    __syncthreads();
    if (tid < NBUCKET) pcount[blockIdx.x * NBUCKET + tid] = lcnt[tid];
}

__global__ __launch_bounds__(512) void offsets_kernel(
        const int* __restrict__ pcount,
        int* __restrict__ gcnt, int* __restrict__ goff, int* __restrict__ gcur) {
    __shared__ int wsum[8];
    int t = threadIdx.x;
    int c = 0;
    for (int b = 0; b < NBLK; ++b) c += pcount[b * NBUCKET + t];
    int lane = t & 63, wid = t >> 6;
    int inc = c;
#pragma unroll
    for (int o = 1; o < 64; o <<= 1) {
        int a = __shfl_up(inc, o);
        if (lane >= o) inc += a;
    }
    if (lane == 63) wsum[wid] = inc;
    __syncthreads();
    int off = 0;
    for (int j = 0; j < wid; ++j) off += wsum[j];
    int excl = off + inc - c;
    gcnt[t] = c;
    goff[t] = excl;
    gcur[t] = excl;
}

__global__ __launch_bounds__(1024) void emit_kernel(
        const float4* __restrict__ recA, const float4* __restrict__ recB,
        int* __restrict__ gcur, float4* __restrict__ items) {
    __shared__ int lcnt[NBUCKET];
    __shared__ int lbase[NBUCKET];
    int tid = threadIdx.x;
    if (tid < NBUCKET) lcnt[tid] = 0;
    __syncthreads();
    int n = blockIdx.x * 1024 + tid;
    bool valid = n < NUM_NETS;
    float4 ra, rb;
    int kx1 = 0, kx2 = 0, ky1 = 0, ky2 = 0;
    if (valid) {
        ra = recA[n]; rb = recB[n];
        unsigned pkx = __float_as_uint(rb.z), pky = __float_as_uint(rb.w);
        kx1 = (int)(pkx & 0xffffu); kx2 = (int)(pkx >> 16);
        ky1 = (int)(pky & 0xffffu); ky2 = (int)(pky >> 16);
#pragma unroll
        for (int cx = 0; cx < 2; ++cx) {
            int kx = cx ? kx2 : kx1;
#pragma unroll
            for (int cy = 0; cy < 2; ++cy) {
                int ky = cy ? ky2 : ky1;
                for_each_bucket(kx, ky, [&](int b) { atomicAdd(&lcnt[b], 1); });
            }
        }
    }
    __syncthreads();
    if (tid < NBUCKET) {
        lbase[tid] = atomicAdd(&gcur[tid], lcnt[tid]);
        lcnt[tid] = 0;
    }
    __syncthreads();
    if (valid) {
        float xmn = ra.x, xmx = ra.y, ymn = ra.z, ymx = ra.w;
        float wh = rb.x, wv = rb.y;
#pragma unroll
        for (int cx = 0; cx < 2; ++cx) {
            int   kx = cx ? kx2 : kx1;
            float xc = cx ? xmx : xmn;
#pragma unroll
            for (int cy = 0; cy < 2; ++cy) {
                int   ky = cy ? ky2 : ky1;
                float yc = cy ? ymx : ymn;
                float sg = (cx ^ cy) ? -1.0f : 1.0f;
                float4 item = make_float4(xc, yc, sg * wh, sg * wv);
                for_each_bucket(kx, ky, [&](int b) {
                    int rank = atomicAdd(&lcnt[b], 1);
                    int pos  = lbase[b] + rank;
                    if (pos < ITEMS_MAX) items[pos] = item;
                });
            }
        }
    }
}

__global__ __launch_bounds__(256) void accum_kernel(
        const float4* __restrict__ items,
        const int* __restrict__ gcnt, const int* __restrict__ goff,
        float* __restrict__ Uh, float* __restrict__ Uv) {
    __shared__ float accH[SW * SLH];
    __shared__ float accV[SW * SLH];
    int b  = blockIdx.x;
    int st = b >> 3, sl = b & 7;
    int x0 = st * SW, y0 = sl * SLH;
    int tid = threadIdx.x;
    for (int k = tid; k < SW * SLH; k += 256) { accH[k] = 0.f; accV[k] = 0.f; }
    __syncthreads();
    int i0  = goff[b];
    int end = min(i0 + gcnt[b], ITEMS_MAX);
    for (int q = i0 + tid; q < end; q += 256) {
        float4 it = items[q];
        int kx = min(NB - 1, (int)(it.x * INV_H));
        int ky = min(NB - 1, (int)(it.y * INV_H));
        float dx0 = (kx + 1) * BIN_H - it.x;
        float dx1 = it.x - kx * BIN_H;
        float dy0 = (ky + 1) * BIN_H - it.y;
        float dy1 = it.y - ky * BIN_H;
        int gy = ky - y0;
        bool ok0 = (unsigned)gy < (unsigned)SLH;
        bool ok1 = ((unsigned)(gy + 1) < (unsigned)SLH) && (ky + 1 < NB);
        int c = kx - x0;
#pragma unroll
        for (int cc = 0; cc < 2; ++cc) {
            int col = c + cc;
            if ((unsigned)col < SW) {
                float dx = cc ? dx1 : dx0;
                if (ok0) {
                    int i = col * SLH + gy;
                    atomicAdd(&accH[i], it.z * dx * dy0);
                    atomicAdd(&accV[i], it.w * dx * dy0);
                }
                if (ok1) {
                    int i = col * SLH + gy + 1;
                    atomicAdd(&accH[i], it.z * dx * dy1);
                    atomicAdd(&accV[i], it.w * dx * dy1);
                }
            }
        }
    }
    __syncthreads();
    for (int k = tid; k < SW * SLH; k += 256) {
        int col = k >> 6, y = k & (SLH - 1);
        int gi = (x0 + col) * NB + y0 + y;
        Uh[gi] = accH[k];
        Uv[gi] = accV[k];
    }
}

__global__ void rowscan_kernel(float* __restrict__ Uh, float* __restrict__ Uv) {
    __shared__ float swh[8], swv[8];
    int x = blockIdx.x, tid = threadIdx.x;
    int lane = tid & 63, wid = tid >> 6;
    float h = Uh[x * NB + tid];
    float v = Uv[x * NB + tid];
#pragma unroll
    for (int o = 1; o < 64; o <<= 1) {
        float a = __shfl_up(h, o);
        float b = __shfl_up(v, o);
        if (lane >= o) { h += a; v += b; }
    }
    if (lane == 63) { swh[wid] = h; swv[wid] = v; }
    __syncthreads();
    float oh = 0.f, ov = 0.f;
    for (int j = 0; j < wid; ++j) { oh += swh[j]; ov += swv[j]; }
    Uh[x * NB + tid] = h + oh;
    Uv[x * NB + tid] = v + ov;
}

__global__ void colscan_partial_kernel(float* __restrict__ Uh,
                                       float* __restrict__ Uv,
                                       float* __restrict__ totH,
                                       float* __restrict__ totV) {
    int s = blockIdx.x;
    int t = blockIdx.y * blockDim.x + threadIdx.x;
    float h = 0.f, v = 0.f;
#pragma unroll
    for (int i = 0; i < STRIPE; ++i) {
        int row = s * STRIPE + i;
        h += Uh[row * NB + t];  Uh[row * NB + t] = h;
        v += Uv[row * NB + t];  Uv[row * NB + t] = v;
    }
    totH[s * NB + t] = h;
    totV[s * NB + t] = v;
}

__global__ void colscan_finish_kernel(const float* __restrict__ Uh,
                                      const float* __restrict__ Uv,
                                      const float* __restrict__ totH,
                                      const float* __restrict__ totV,
                                      float* __restrict__ out) {
    int s = blockIdx.x;
    int t = blockIdx.y * blockDim.x + threadIdx.x;
    float offh = 0.f, offv = 0.f;
    for (int s2 = 0; s2 < s; ++s2) {
        offh += totH[s2 * NB + t];
        offv += totV[s2 * NB + t];
    }
#pragma unroll
    for (int i = 0; i < STRIPE; ++i) {
        int row = s * STRIPE + i;
        float h = fabsf(Uh[row * NB + t] + offh) * OUT_SCALE;
        float v = fabsf(Uv[row * NB + t] + offv) * OUT_SCALE;
        float m = fmaxf(h, v);
        out[row * NB + t] = fminf(fmaxf(m * m, 0.5f), 2.0f);
    }
}

__global__ void scatter_kernel(const float* __restrict__ pin_pos,
                               const int*   __restrict__ flat_netpin,
                               const float* __restrict__ net_weights,
                               float* __restrict__ Uh,
                               float* __restrict__ Uv) {
    int n = blockIdx.x * blockDim.x + threadIdx.x;
    if (n >= NUM_NETS) return;
    float xmn = 1e30f, xmx = -1e30f, ymn = 1e30f, ymx = -1e30f;
#pragma unroll
    for (int p = 0; p < PINS_PER_NET; ++p) {
        int pi  = flat_netpin[n * PINS_PER_NET + p];
        float x = pin_pos[pi];
        float y = pin_pos[NUM_PINS + pi];
        xmn = fminf(xmn, x); xmx = fmaxf(xmx, x);
        ymn = fminf(ymn, y); ymx = fmaxf(ymx, y);
    }
    float w  = net_weights[n];
    float wh = w / (ymx - ymn), wv = w / (xmx - xmn);
    int kx1 = min(NB - 1, (int)(xmn * INV_H));
    int kx2 = min(NB - 1, (int)(xmx * INV_H));
    int ky1 = min(NB - 1, (int)(ymn * INV_H));
    int ky2 = min(NB - 1, (int)(ymx * INV_H));
    int   xi[4] = { kx1, kx1 + 1, kx2, kx2 + 1 };
    float xv[4] = { (kx1 + 1) * BIN_H - xmn,  xmn - kx1 * BIN_H,
                    xmx - (kx2 + 1) * BIN_H,  kx2 * BIN_H - xmx };
    int   yi[4] = { ky1, ky1 + 1, ky2, ky2 + 1 };
    float yv[4] = { (ky1 + 1) * BIN_H - ymn,  ymn - ky1 * BIN_H,
                    ymx - (ky2 + 1) * BIN_H,  ky2 * BIN_H - ymx };
#pragma unroll
    for (int a = 0; a < 4; ++a) {
        if (xi[a] >= NB) continue;
#pragma unroll
        for (int b2 = 0; b2 < 4; ++b2) {
            if (yi[b2] >= NB) continue;
            float prod = xv[a] * yv[b2];
            atomicAdd(&Uh[xi[a] * NB + yi[b2]], wh * prod);
            atomicAdd(&Uv[xi[a] * NB + yi[b2]], wv * prod);
        }
    }
}

__global__ void fb_rowscan_kernel(float* __restrict__ Uh, float* __restrict__ Uv) {
    __shared__ float sh[NB];
    __shared__ float sv[NB];
    int rr = blockIdx.x, t = threadIdx.x;
    sh[t] = Uh[rr * NB + t];
    sv[t] = Uv[rr * NB + t];
    __syncthreads();
#pragma unroll
    for (int off = 1; off < NB; off <<= 1) {
        float a = (t >= off) ? sh[t - off] : 0.0f;
        float b = (t >= off) ? sv[t - off] : 0.0f;
        __syncthreads();
        sh[t] += a; sv[t] += b;
        __syncthreads();
    }
    Uh[rr * NB + t] = sh[t];
    Uv[rr * NB + t] = sv[t];
}

__global__ void fb_colscan_kernel(const float* __restrict__ Uh,
                                  const float* __restrict__ Uv,
                                  float* __restrict__ out) {
    int t = blockIdx.x * blockDim.x + threadIdx.x;
    if (t >= NB) return;
    float sh = 0.f, sv = 0.f;
    for (int i = 0; i < NB; ++i) {
        sh += Uh[i * NB + t];
        sv += Uv[i * NB + t];
        float h = fabsf(sh) * OUT_SCALE;
        float v = fabsf(sv) * OUT_SCALE;
        float m = fmaxf(h, v);
        out[i * NB + t] = fminf(fmaxf(m * m, 0.5f), 2.0f);
    }
}

extern "C" void kernel_launch(void* const* d_in, const int* in_sizes, int n_in,
                              void* d_out, int out_size, void* d_ws, size_t ws_size,
                              hipStream_t stream) {
    const float* pin_pos     = (const float*)d_in[0];
    const int*   flat_netpin = (const int*)d_in[2];
    const float* net_weights = (const float*)d_in[3];
    float* out = (float*)d_out;
    float* ws  = (float*)d_ws;

    /* layout (floats):
       recA[400K] recB[400K] pcnt[GBLK*512] gcnt[512] goff[512] gcur[512]
       items[ITEMS_MAX*4] Uh[256K] Uv[256K] Th[32K] Tv[32K]  (~23.5 MB) */
    const size_t o_recA = 0;
    const size_t o_recB = o_recA + (size_t)NUM_NETS * 4;
    const size_t o_pcnt = o_recB + (size_t)NUM_NETS * 4;
    const size_t o_gcnt = o_pcnt + (size_t)GBLK * NBUCKET;
    const size_t o_goff = o_gcnt + NBUCKET;
    const size_t o_gcur = o_goff + NBUCKET;
    const size_t o_itm  = (o_gcur + NBUCKET + 3) & ~(size_t)3;
    const size_t o_Uh   = o_itm + (size_t)ITEMS_MAX * 4;
    const size_t o_Uv   = o_Uh + (size_t)NB * NB;
    const size_t o_Th   = o_Uv + (size_t)NB * NB;
    const size_t o_Tv   = o_Th + (size_t)NSTRIPE * NB;
    const size_t need   = o_Tv + (size_t)NSTRIPE * NB;

    if (ws_size < need * sizeof(float)) {
        float* Uh = ws;
        float* Uv = ws + (size_t)NB * NB;
        hipMemsetAsync(ws, 0, 2 * (size_t)NB * NB * sizeof(float), stream);
        scatter_kernel<<<(NUM_NETS + 255) / 256, 256, 0, stream>>>(
            pin_pos, flat_netpin, net_weights, Uh, Uv);
        fb_rowscan_kernel<<<NB, NB, 0, stream>>>(Uh, Uv);
        fb_colscan_kernel<<<2, 256, 0, stream>>>(Uh, Uv, out);
        return;
    }

    float4* recA  = (float4*)(ws + o_recA);
    float4* recB  = (float4*)(ws + o_recB);
    int*    pcnt  = (int*)(ws + o_pcnt);
    int*    gcnt  = (int*)(ws + o_gcnt);
    int*    goff  = (int*)(ws + o_goff);
    int*    gcur  = (int*)(ws + o_gcur);
    float4* items = (float4*)(ws + o_itm);
    float*  Uh    = ws + o_Uh;
    float*  Uv    = ws + o_Uv;
    float*  Th    = ws + o_Th;
    float*  Tv    = ws + o_Tv;

    void* args[] = { (void*)&pin_pos, (void*)&flat_netpin, (void*)&net_weights,
                     (void*)&recA, (void*)&recB, (void*)&pcnt, (void*)&gcnt,
                     (void*)&goff, (void*)&gcur, (void*)&items,
                     (void*)&Uh, (void*)&Uv, (void*)&Th, (void*)&Tv,
                     (void*)&out };
    hipError_t err = hipLaunchCooperativeKernel(
        (const void*)fused_kernel, dim3(GBLK), dim3(TPB), args, 0, stream);

    if (err != hipSuccess) {
        /* proven multi-kernel path */
        bbox_count_kernel<<<NBLK, 1024, 0, stream>>>(
            pin_pos, flat_netpin, net_weights, recA, recB, pcnt);
        offsets_kernel<<<1, 512, 0, stream>>>(pcnt, gcnt, goff, gcur);
        emit_kernel<<<NBLK, 1024, 0, stream>>>(recA, recB, gcur, items);
        accum_kernel<<<NBUCKET, 256, 0, stream>>>(items, gcnt, goff, Uh, Uv);
        rowscan_kernel<<<NB, NB, 0, stream>>>(Uh, Uv);
        colscan_partial_kernel<<<dim3(NSTRIPE, 4), 128, 0, stream>>>(Uh, Uv, Th, Tv);
        colscan_finish_kernel<<<dim3(NSTRIPE, 4), 128, 0, stream>>>(Uh, Uv, Th, Tv, out);
    }
}

// Round 11
// 160.356 us; speedup vs baseline: 2.9057x; 2.9057x over previous
//
#include <hip/hip_runtime.h>

#define NUM_NETS     100000
#define PINS_PER_NET 5
#define NUM_PINS     (NUM_NETS * PINS_PER_NET)
#define NB           512
#define BIN_H        1.953125f          /* 1000/512, exact in fp32 */
#define INV_H        0.512f             /* 512/1000 */
#define OUT_SCALE    (1.0f / 195.3125f) /* 1/(BIN_SIZE_X * 100 tracks) */

#define SW           8                  /* stripe width (x bins) */
#define NSTRIPES     (NB / SW)          /* 64 */
#define NSLICE       8                  /* y slices */
#define SLH          (NB / NSLICE)      /* 64 */
#define NBUCKET      (NSTRIPES * NSLICE)/* 512 */
#define NBLK         ((NUM_NETS + 1023) / 1024)  /* 98 */
#define ITEMS_MAX    1048576
#define ITEMS_FIXED  524288             /* linear-read probe window */
#define STRIPE       8
#define NSTRIPE      (NB / STRIPE)      /* 64 */

// bucket id for cluster cell (kx,ky): stripe kx>>3, slice ky>>6
template <class F>
__device__ __forceinline__ void for_each_bucket(int kx, int ky, F&& f) {
    int s0 = kx >> 3, t0 = ky >> 6;
    int s1 = (kx + 1 < NB && ((kx + 1) >> 3) != s0) ? ((kx + 1) >> 3) : -1;
    int t1 = (ky + 1 < NB && ((ky + 1) >> 6) != t0) ? ((ky + 1) >> 6) : -1;
    f(s0 * NSLICE + t0);
    if (s1 >= 0)            f(s1 * NSLICE + t0);
    if (t1 >= 0)            f(s0 * NSLICE + t1);
    if (s1 >= 0 && t1 >= 0) f(s1 * NSLICE + t1);
}

// ---------------------------------------------------------------------------
// A: gather pins once -> bbox records + per-block bucket counts.
// ---------------------------------------------------------------------------
__global__ __launch_bounds__(1024) void bbox_count_kernel(
        const float* __restrict__ pin_pos,
        const int*   __restrict__ flat_netpin,
        const float* __restrict__ net_weights,
        float4* __restrict__ recA, float4* __restrict__ recB,
        int* __restrict__ pcount) {
    __shared__ int lcnt[NBUCKET];
    int tid = threadIdx.x;
    if (tid < NBUCKET) lcnt[tid] = 0;
    __syncthreads();
    int n = blockIdx.x * 1024 + tid;
    if (n < NUM_NETS) {
        float xmn = 1e30f, xmx = -1e30f, ymn = 1e30f, ymx = -1e30f;
#pragma unroll
        for (int p = 0; p < PINS_PER_NET; ++p) {
            int pi  = flat_netpin[n * PINS_PER_NET + p];
            float x = pin_pos[pi];
            float y = pin_pos[NUM_PINS + pi];
            xmn = fminf(xmn, x); xmx = fmaxf(xmx, x);
            ymn = fminf(ymn, y); ymx = fmaxf(ymx, y);
        }
        float w = net_weights[n];
        int kx1 = min(NB - 1, (int)(xmn * INV_H));
        int kx2 = min(NB - 1, (int)(xmx * INV_H));
        int ky1 = min(NB - 1, (int)(ymn * INV_H));
        int ky2 = min(NB - 1, (int)(ymx * INV_H));
        recA[n] = make_float4(xmn, xmx, ymn, ymx);
        recB[n] = make_float4(w / (ymx - ymn), w / (xmx - xmn),
                              __uint_as_float((unsigned)kx1 | ((unsigned)kx2 << 16)),
                              __uint_as_float((unsigned)ky1 | ((unsigned)ky2 << 16)));
#pragma unroll
        for (int cx = 0; cx < 2; ++cx) {
            int kx = cx ? kx2 : kx1;
#pragma unroll
            for (int cy = 0; cy < 2; ++cy) {
                int ky = cy ? ky2 : ky1;
                for_each_bucket(kx, ky, [&](int b) { atomicAdd(&lcnt[b], 1); });
            }
        }
    }
    __syncthreads();
    if (tid < NBUCKET) pcount[blockIdx.x * NBUCKET + tid] = lcnt[tid];
}

// ---------------------------------------------------------------------------
// B: bucket totals + exclusive offsets + cursor init (1 block, 512 thr)
// ---------------------------------------------------------------------------
__global__ __launch_bounds__(512) void offsets_kernel(
        const int* __restrict__ pcount,
        int* __restrict__ gcnt, int* __restrict__ goff, int* __restrict__ gcur) {
    __shared__ int wsum[8];
    int t = threadIdx.x;
    int c = 0;
    for (int b = 0; b < NBLK; ++b) c += pcount[b * NBUCKET + t];
    int lane = t & 63, wid = t >> 6;
    int inc = c;
#pragma unroll
    for (int o = 1; o < 64; o <<= 1) {
        int a = __shfl_up(inc, o);
        if (lane >= o) inc += a;
    }
    if (lane == 63) wsum[wid] = inc;
    __syncthreads();
    int off = 0;
    for (int j = 0; j < wid; ++j) off += wsum[j];
    int excl = off + inc - c;
    gcnt[t] = c;
    goff[t] = excl;
    gcur[t] = excl;
}

// ---------------------------------------------------------------------------
// C: emit items {x,y,±wh,±wv} into exact per-bucket segments
// ---------------------------------------------------------------------------
__global__ __launch_bounds__(1024) void emit_kernel(
        const float4* __restrict__ recA, const float4* __restrict__ recB,
        int* __restrict__ gcur, float4* __restrict__ items) {
    __shared__ int lcnt[NBUCKET];
    __shared__ int lbase[NBUCKET];
    int tid = threadIdx.x;
    if (tid < NBUCKET) lcnt[tid] = 0;
    __syncthreads();
    int n = blockIdx.x * 1024 + tid;
    bool valid = n < NUM_NETS;
    float4 ra, rb;
    int kx1 = 0, kx2 = 0, ky1 = 0, ky2 = 0;
    if (valid) {
        ra = recA[n]; rb = recB[n];
        unsigned pkx = __float_as_uint(rb.z), pky = __float_as_uint(rb.w);
        kx1 = (int)(pkx & 0xffffu); kx2 = (int)(pkx >> 16);
        ky1 = (int)(pky & 0xffffu); ky2 = (int)(pky >> 16);
#pragma unroll
        for (int cx = 0; cx < 2; ++cx) {
            int kx = cx ? kx2 : kx1;
#pragma unroll
            for (int cy = 0; cy < 2; ++cy) {
                int ky = cy ? ky2 : ky1;
                for_each_bucket(kx, ky, [&](int b) { atomicAdd(&lcnt[b], 1); });
            }
        }
    }
    __syncthreads();
    if (tid < NBUCKET) {
        lbase[tid] = atomicAdd(&gcur[tid], lcnt[tid]);
        lcnt[tid] = 0;
    }
    __syncthreads();
    if (valid) {
        float xmn = ra.x, xmx = ra.y, ymn = ra.z, ymx = ra.w;
        float wh = rb.x, wv = rb.y;
#pragma unroll
        for (int cx = 0; cx < 2; ++cx) {
            int   kx = cx ? kx2 : kx1;
            float xc = cx ? xmx : xmn;
#pragma unroll
            for (int cy = 0; cy < 2; ++cy) {
                int   ky = cy ? ky2 : ky1;
                float yc = cy ? ymx : ymn;
                float sg = (cx ^ cy) ? -1.0f : 1.0f;
                float4 item = make_float4(xc, yc, sg * wh, sg * wv);
                for_each_bucket(kx, ky, [&](int b) {
                    int rank = atomicAdd(&lcnt[b], 1);
                    int pos  = lbase[b] + rank;
                    if (pos < ITEMS_MAX) items[pos] = item;
                });
            }
        }
    }
}

// ---------------------------------------------------------------------------
// PROBE 0: dispatch floor
// ---------------------------------------------------------------------------
__global__ __launch_bounds__(256) void noop_kernel(float* __restrict__ dummy) {
    if (blockIdx.x == 0 && threadIdx.x == 0) dummy[0] = 1.0f;
}

// ---------------------------------------------------------------------------
// PROBE 1: linear read of the fresh items buffer (first consumer)
// ---------------------------------------------------------------------------
__global__ __launch_bounds__(256) void read_lin_kernel(
        const float4* __restrict__ items, float* __restrict__ dummy) {
    int bid = blockIdx.x, tid = threadIdx.x;
    int per = ITEMS_FIXED / 512;           /* 1024 items per block */
    int base = bid * per;
    float s = 0.f;
    for (int q = base + tid; q < base + per; q += 256) {
        float4 v = items[q];
        s += v.x + v.y + v.z + v.w;
    }
    dummy[bid * 256 + tid] = s;
}

// ---------------------------------------------------------------------------
// PROBE 2: per-bucket segment read (accum addressing, no LDS/compute)
// ---------------------------------------------------------------------------
__global__ __launch_bounds__(256) void read_seg_kernel(
        const float4* __restrict__ items,
        const int* __restrict__ gcnt, const int* __restrict__ goff,
        float* __restrict__ dummy) {
    int b = blockIdx.x, tid = threadIdx.x;
    int i0 = goff[b];
    int end = min(i0 + gcnt[b], ITEMS_MAX);
    float s = 0.f;
    for (int q = i0 + tid; q < end; q += 256) {
        float4 v = items[q];
        s += v.x + v.y + v.z + v.w;
    }
    dummy[b * 256 + tid] = s;
}

// ---------------------------------------------------------------------------
// PROBE 3: accum's LDS-atomic/compute pattern, zero global reads
// ---------------------------------------------------------------------------
__global__ __launch_bounds__(256) void compute_only_kernel(
        const int* __restrict__ gcnt,
        float* __restrict__ Uh2, float* __restrict__ Uv2) {
    __shared__ float accH[SW * SLH];
    __shared__ float accV[SW * SLH];
    int b = blockIdx.x, tid = threadIdx.x;
    for (int k = tid; k < SW * SLH; k += 256) { accH[k] = 0.f; accV[k] = 0.f; }
    __syncthreads();
    int cnt = min(gcnt[b], ITEMS_MAX);
    for (int q = tid; q < cnt; q += 256) {
        unsigned h = (unsigned)q * 2654435761u ^ (unsigned)b * 40503u;
        int col = (int)(h & 7);
        int gy  = (int)((h >> 3) % 63);
        float dx0 = (float)((h >> 9) & 1023) * 0.001f;
        float dx1 = 1.9f - dx0;
        float dy0 = (float)((h >> 19) & 1023) * 0.001f;
        float dy1 = 1.9f - dy0;
        float wz = dx0 * 0.3f, ww = dy1 * 0.7f;
        int i = col * SLH + gy;
        atomicAdd(&accH[i], wz * dy0);     atomicAdd(&accV[i], ww * dy0);
        atomicAdd(&accH[i + 1], wz * dy1); atomicAdd(&accV[i + 1], ww * dy1);
        int i2 = ((col + 1) & 7) * SLH + gy;
        atomicAdd(&accH[i2], wz * dx1);     atomicAdd(&accV[i2], ww * dx1);
        atomicAdd(&accH[i2 + 1], wz * dx0); atomicAdd(&accV[i2 + 1], ww * dx0);
    }
    __syncthreads();
    int st = b >> 3, sl = b & 7;
    int x0 = st * SW, y0 = sl * SLH;
    for (int k = tid; k < SW * SLH; k += 256) {
        int col = k >> 6, y = k & (SLH - 1);
        int gi = (x0 + col) * NB + y0 + y;
        Uh2[gi] = accH[k];
        Uv2[gi] = accV[k];
    }
}

// ---------------------------------------------------------------------------
// D: per-bucket accumulate (functional, third consumer of items)
// ---------------------------------------------------------------------------
__global__ __launch_bounds__(256) void accum_kernel(
        const float4* __restrict__ items,
        const int* __restrict__ gcnt, const int* __restrict__ goff,
        float* __restrict__ Uh, float* __restrict__ Uv) {
    __shared__ float accH[SW * SLH];
    __shared__ float accV[SW * SLH];
    int b  = blockIdx.x;
    int st = b >> 3, sl = b & 7;
    int x0 = st * SW, y0 = sl * SLH;
    int tid = threadIdx.x;
    for (int k = tid; k < SW * SLH; k += 256) { accH[k] = 0.f; accV[k] = 0.f; }
    __syncthreads();
    int i0  = goff[b];
    int end = min(i0 + gcnt[b], ITEMS_MAX);
    for (int q = i0 + tid; q < end; q += 256) {
        float4 it = items[q];
        int kx = min(NB - 1, (int)(it.x * INV_H));
        int ky = min(NB - 1, (int)(it.y * INV_H));
        float dx0 = (kx + 1) * BIN_H - it.x;
        float dx1 = it.x - kx * BIN_H;
        float dy0 = (ky + 1) * BIN_H - it.y;
        float dy1 = it.y - ky * BIN_H;
        int gy = ky - y0;
        bool ok0 = (unsigned)gy < (unsigned)SLH;
        bool ok1 = ((unsigned)(gy + 1) < (unsigned)SLH) && (ky + 1 < NB);
        int c = kx - x0;
#pragma unroll
        for (int cc = 0; cc < 2; ++cc) {
            int col = c + cc;
            if ((unsigned)col < SW) {
                float dx = cc ? dx1 : dx0;
                if (ok0) {
                    int i = col * SLH + gy;
                    atomicAdd(&accH[i], it.z * dx * dy0);
                    atomicAdd(&accV[i], it.w * dx * dy0);
                }
                if (ok1) {
                    int i = col * SLH + gy + 1;
                    atomicAdd(&accH[i], it.z * dx * dy1);
                    atomicAdd(&accV[i], it.w * dx * dy1);
                }
            }
        }
    }
    __syncthreads();
    for (int k = tid; k < SW * SLH; k += 256) {
        int col = k >> 6, y = k & (SLH - 1);
        int gi = (x0 + col) * NB + y0 + y;
        Uh[gi] = accH[k];
        Uv[gi] = accV[k];
    }
}

// ---------------------------------------------------------------------------
// E/F/G: scans + epilogue (unchanged)
// ---------------------------------------------------------------------------
__global__ void rowscan_kernel(float* __restrict__ Uh, float* __restrict__ Uv) {
    __shared__ float swh[8], swv[8];
    int x = blockIdx.x, tid = threadIdx.x;
    int lane = tid & 63, wid = tid >> 6;
    float h = Uh[x * NB + tid];
    float v = Uv[x * NB + tid];
#pragma unroll
    for (int o = 1; o < 64; o <<= 1) {
        float a = __shfl_up(h, o);
        float b = __shfl_up(v, o);
        if (lane >= o) { h += a; v += b; }
    }
    if (lane == 63) { swh[wid] = h; swv[wid] = v; }
    __syncthreads();
    float oh = 0.f, ov = 0.f;
    for (int j = 0; j < wid; ++j) { oh += swh[j]; ov += swv[j]; }
    Uh[x * NB + tid] = h + oh;
    Uv[x * NB + tid] = v + ov;
}

__global__ void colscan_partial_kernel(float* __restrict__ Uh,
                                       float* __restrict__ Uv,
                                       float* __restrict__ totH,
                                       float* __restrict__ totV) {
    int s = blockIdx.x;
    int t = blockIdx.y * blockDim.x + threadIdx.x;
    float h = 0.f, v = 0.f;
#pragma unroll
    for (int i = 0; i < STRIPE; ++i) {
        int row = s * STRIPE + i;
        h += Uh[row * NB + t];  Uh[row * NB + t] = h;
        v += Uv[row * NB + t];  Uv[row * NB + t] = v;
    }
    totH[s * NB + t] = h;
    totV[s * NB + t] = v;
}

__global__ void colscan_finish_kernel(const float* __restrict__ Uh,
                                      const float* __restrict__ Uv,
                                      const float* __restrict__ totH,
                                      const float* __restrict__ totV,
                                      float* __restrict__ out) {
    int s = blockIdx.x;
    int t = blockIdx.y * blockDim.x + threadIdx.x;
    float offh = 0.f, offv = 0.f;
    for (int s2 = 0; s2 < s; ++s2) {
        offh += totH[s2 * NB + t];
        offv += totV[s2 * NB + t];
    }
#pragma unroll
    for (int i = 0; i < STRIPE; ++i) {
        int row = s * STRIPE + i;
        float h = fabsf(Uh[row * NB + t] + offh) * OUT_SCALE;
        float v = fabsf(Uv[row * NB + t] + offv) * OUT_SCALE;
        float m = fmaxf(h, v);
        out[row * NB + t] = fminf(fmaxf(m * m, 0.5f), 2.0f);
    }
}

// ---------------------------------------------------------------------------
// Fallback (tiny workspace): global-atomic scatter + scans
// ---------------------------------------------------------------------------
__global__ void scatter_kernel(const float* __restrict__ pin_pos,
                               const int*   __restrict__ flat_netpin,
                               const float* __restrict__ net_weights,
                               float* __restrict__ Uh,
                               float* __restrict__ Uv) {
    int n = blockIdx.x * blockDim.x + threadIdx.x;
    if (n >= NUM_NETS) return;
    float xmn = 1e30f, xmx = -1e30f, ymn = 1e30f, ymx = -1e30f;
#pragma unroll
    for (int p = 0; p < PINS_PER_NET; ++p) {
        int pi  = flat_netpin[n * PINS_PER_NET + p];
        float x = pin_pos[pi];
        float y = pin_pos[NUM_PINS + pi];
        xmn = fminf(xmn, x); xmx = fmaxf(xmx, x);
        ymn = fminf(ymn, y); ymx = fmaxf(ymx, y);
    }
    float w  = net_weights[n];
    float wh = w / (ymx - ymn), wv = w / (xmx - xmn);
    int kx1 = min(NB - 1, (int)(xmn * INV_H));
    int kx2 = min(NB - 1, (int)(xmx * INV_H));
    int ky1 = min(NB - 1, (int)(ymn * INV_H));
    int ky2 = min(NB - 1, (int)(ymx * INV_H));
    int   xi[4] = { kx1, kx1 + 1, kx2, kx2 + 1 };
    float xv[4] = { (kx1 + 1) * BIN_H - xmn,  xmn - kx1 * BIN_H,
                    xmx - (kx2 + 1) * BIN_H,  kx2 * BIN_H - xmx };
    int   yi[4] = { ky1, ky1 + 1, ky2, ky2 + 1 };
    float yv[4] = { (ky1 + 1) * BIN_H - ymn,  ymn - ky1 * BIN_H,
                    ymx - (ky2 + 1) * BIN_H,  ky2 * BIN_H - ymx };
#pragma unroll
    for (int a = 0; a < 4; ++a) {
        if (xi[a] >= NB) continue;
#pragma unroll
        for (int b2 = 0; b2 < 4; ++b2) {
            if (yi[b2] >= NB) continue;
            float prod = xv[a] * yv[b2];
            atomicAdd(&Uh[xi[a] * NB + yi[b2]], wh * prod);
            atomicAdd(&Uv[xi[a] * NB + yi[b2]], wv * prod);
        }
    }
}

__global__ void fb_rowscan_kernel(float* __restrict__ Uh, float* __restrict__ Uv) {
    __shared__ float sh[NB];
    __shared__ float sv[NB];
    int rr = blockIdx.x, t = threadIdx.x;
    sh[t] = Uh[rr * NB + t];
    sv[t] = Uv[rr * NB + t];
    __syncthreads();
#pragma unroll
    for (int off = 1; off < NB; off <<= 1) {
        float a = (t >= off) ? sh[t - off] : 0.0f;
        float b = (t >= off) ? sv[t - off] : 0.0f;
        __syncthreads();
        sh[t] += a; sv[t] += b;
        __syncthreads();
    }
    Uh[rr * NB + t] = sh[t];
    Uv[rr * NB + t] = sv[t];
}

__global__ void fb_colscan_kernel(const float* __restrict__ Uh,
                                  const float* __restrict__ Uv,
                                  float* __restrict__ out) {
    int t = blockIdx.x * blockDim.x + threadIdx.x;
    if (t >= NB) return;
    float sh = 0.f, sv = 0.f;
    for (int i = 0; i < NB; ++i) {
        sh += Uh[i * NB + t];
        sv += Uv[i * NB + t];
        float h = fabsf(sh) * OUT_SCALE;
        float v = fabsf(sv) * OUT_SCALE;
        float m = fmaxf(h, v);
        out[i * NB + t] = fminf(fmaxf(m * m, 0.5f), 2.0f);
    }
}

extern "C" void kernel_launch(void* const* d_in, const int* in_sizes, int n_in,
                              void* d_out, int out_size, void* d_ws, size_t ws_size,
                              hipStream_t stream) {
    const float* pin_pos     = (const float*)d_in[0];
    const int*   flat_netpin = (const int*)d_in[2];
    const float* net_weights = (const float*)d_in[3];
    float* out = (float*)d_out;
    float* ws  = (float*)d_ws;

    /* layout (floats): functional regions exactly as R9, probes appended */
    const size_t o_recA = 0;
    const size_t o_recB = o_recA + (size_t)NUM_NETS * 4;
    const size_t o_pcnt = o_recB + (size_t)NUM_NETS * 4;
    const size_t o_gcnt = o_pcnt + (size_t)NBLK * NBUCKET;
    const size_t o_goff = o_gcnt + NBUCKET;
    const size_t o_gcur = o_goff + NBUCKET;
    const size_t o_itm  = (o_gcur + NBUCKET + 3) & ~(size_t)3;
    const size_t o_Uh   = o_itm + (size_t)ITEMS_MAX * 4;
    const size_t o_Uv   = o_Uh + (size_t)NB * NB;
    const size_t o_Th   = o_Uv + (size_t)NB * NB;
    const size_t o_Tv   = o_Th + (size_t)NSTRIPE * NB;
    const size_t o_dmy  = o_Tv + (size_t)NSTRIPE * NB;          /* 512*256 */
    const size_t o_Uh2  = o_dmy + (size_t)NBUCKET * 256;
    const size_t o_Uv2  = o_Uh2 + (size_t)NB * NB;
    const size_t need   = o_Uv2 + (size_t)NB * NB;

    if (ws_size < need * sizeof(float)) {
        float* Uh = ws;
        float* Uv = ws + (size_t)NB * NB;
        hipMemsetAsync(ws, 0, 2 * (size_t)NB * NB * sizeof(float), stream);
        scatter_kernel<<<(NUM_NETS + 255) / 256, 256, 0, stream>>>(
            pin_pos, flat_netpin, net_weights, Uh, Uv);
        fb_rowscan_kernel<<<NB, NB, 0, stream>>>(Uh, Uv);
        fb_colscan_kernel<<<2, 256, 0, stream>>>(Uh, Uv, out);
        return;
    }

    float4* recA  = (float4*)(ws + o_recA);
    float4* recB  = (float4*)(ws + o_recB);
    int*    pcnt  = (int*)(ws + o_pcnt);
    int*    gcnt  = (int*)(ws + o_gcnt);
    int*    goff  = (int*)(ws + o_goff);
    int*    gcur  = (int*)(ws + o_gcur);
    float4* items = (float4*)(ws + o_itm);
    float*  Uh    = ws + o_Uh;
    float*  Uv    = ws + o_Uv;
    float*  Th    = ws + o_Th;
    float*  Tv    = ws + o_Tv;
    float*  dmy   = ws + o_dmy;
    float*  Uh2   = ws + o_Uh2;
    float*  Uv2   = ws + o_Uv2;

    /* ---- functional front half ---- */
    bbox_count_kernel<<<NBLK, 1024, 0, stream>>>(
        pin_pos, flat_netpin, net_weights, recA, recB, pcnt);
    offsets_kernel<<<1, 512, 0, stream>>>(pcnt, gcnt, goff, gcur);
    emit_kernel<<<NBLK, 1024, 0, stream>>>(recA, recB, gcur, items);

    /* ---- probes (scratch-only writes; ordered consumers of items) ---- */
    noop_kernel<<<NBUCKET, 256, 0, stream>>>(dmy);
    read_lin_kernel<<<NBUCKET, 256, 0, stream>>>(items, dmy);
    read_seg_kernel<<<NBUCKET, 256, 0, stream>>>(items, gcnt, goff, dmy);
    compute_only_kernel<<<NBUCKET, 256, 0, stream>>>(gcnt, Uh2, Uv2);

    /* ---- functional back half ---- */
    accum_kernel<<<NBUCKET, 256, 0, stream>>>(items, gcnt, goff, Uh, Uv);
    rowscan_kernel<<<NB, NB, 0, stream>>>(Uh, Uv);
    colscan_partial_kernel<<<dim3(NSTRIPE, 4), 128, 0, stream>>>(Uh, Uv, Th, Tv);
    colscan_finish_kernel<<<dim3(NSTRIPE, 4), 128, 0, stream>>>(Uh, Uv, Th, Tv, out);
}

// Round 12
// 68.077 us; speedup vs baseline: 6.8444x; 2.3555x over previous
//
#include <hip/hip_runtime.h>

#define NUM_NETS     100000
#define PINS_PER_NET 5
#define NUM_PINS     (NUM_NETS * PINS_PER_NET)
#define NB           512
#define BIN_H        1.953125f          /* 1000/512, exact in fp32 */
#define INV_H        0.512f             /* 512/1000 */
#define OUT_SCALE    (1.0f / 195.3125f) /* 1/(BIN_SIZE_X * 100 tracks) */

#define SW           8                  /* stripe width (x bins) */
#define NSTRIPES     (NB / SW)          /* 64 */
#define NSLICE       8                  /* y slices */
#define SLH          (NB / NSLICE)      /* 64 */
#define NBUCKET      (NSTRIPES * NSLICE)/* 512 */
#define NBLK         ((NUM_NETS + 1023) / 1024)  /* 98 */
#define ITEMS_MAX    1048576
#define STRIPE       8
#define NSTRIPE      (NB / STRIPE)      /* 64 */

#define FXS          2097152.0f         /* 2^21 fixed-point scale */
#define INV_FXS      (1.0f / 2097152.0f)

// bucket id for cluster cell (kx,ky): stripe kx>>3, slice ky>>6
template <class F>
__device__ __forceinline__ void for_each_bucket(int kx, int ky, F&& f) {
    int s0 = kx >> 3, t0 = ky >> 6;
    int s1 = (kx + 1 < NB && ((kx + 1) >> 3) != s0) ? ((kx + 1) >> 3) : -1;
    int t1 = (ky + 1 < NB && ((ky + 1) >> 6) != t0) ? ((ky + 1) >> 6) : -1;
    f(s0 * NSLICE + t0);
    if (s1 >= 0)            f(s1 * NSLICE + t0);
    if (t1 >= 0)            f(s0 * NSLICE + t1);
    if (s1 >= 0 && t1 >= 0) f(s1 * NSLICE + t1);
}

// ---------------------------------------------------------------------------
// A: gather pins once -> bbox records + per-block bucket counts.
// ---------------------------------------------------------------------------
__global__ __launch_bounds__(1024) void bbox_count_kernel(
        const float* __restrict__ pin_pos,
        const int*   __restrict__ flat_netpin,
        const float* __restrict__ net_weights,
        float4* __restrict__ recA, float4* __restrict__ recB,
        int* __restrict__ pcount) {
    __shared__ int lcnt[NBUCKET];
    int tid = threadIdx.x;
    if (tid < NBUCKET) lcnt[tid] = 0;
    __syncthreads();
    int n = blockIdx.x * 1024 + tid;
    if (n < NUM_NETS) {
        float xmn = 1e30f, xmx = -1e30f, ymn = 1e30f, ymx = -1e30f;
#pragma unroll
        for (int p = 0; p < PINS_PER_NET; ++p) {
            int pi  = flat_netpin[n * PINS_PER_NET + p];
            float x = pin_pos[pi];
            float y = pin_pos[NUM_PINS + pi];
            xmn = fminf(xmn, x); xmx = fmaxf(xmx, x);
            ymn = fminf(ymn, y); ymx = fmaxf(ymx, y);
        }
        float w = net_weights[n];
        int kx1 = min(NB - 1, (int)(xmn * INV_H));
        int kx2 = min(NB - 1, (int)(xmx * INV_H));
        int ky1 = min(NB - 1, (int)(ymn * INV_H));
        int ky2 = min(NB - 1, (int)(ymx * INV_H));
        recA[n] = make_float4(xmn, xmx, ymn, ymx);
        recB[n] = make_float4(w / (ymx - ymn), w / (xmx - xmn),
                              __uint_as_float((unsigned)kx1 | ((unsigned)kx2 << 16)),
                              __uint_as_float((unsigned)ky1 | ((unsigned)ky2 << 16)));
#pragma unroll
        for (int cx = 0; cx < 2; ++cx) {
            int kx = cx ? kx2 : kx1;
#pragma unroll
            for (int cy = 0; cy < 2; ++cy) {
                int ky = cy ? ky2 : ky1;
                for_each_bucket(kx, ky, [&](int b) { atomicAdd(&lcnt[b], 1); });
            }
        }
    }
    __syncthreads();
    if (tid < NBUCKET) pcount[blockIdx.x * NBUCKET + tid] = lcnt[tid];
}

// ---------------------------------------------------------------------------
// B: bucket totals + exclusive offsets + cursor init (1 block, 512 thr)
// ---------------------------------------------------------------------------
__global__ __launch_bounds__(512) void offsets_kernel(
        const int* __restrict__ pcount,
        int* __restrict__ gcnt, int* __restrict__ goff, int* __restrict__ gcur) {
    __shared__ int wsum[8];
    int t = threadIdx.x;
    int c = 0;
    for (int b = 0; b < NBLK; ++b) c += pcount[b * NBUCKET + t];
    int lane = t & 63, wid = t >> 6;
    int inc = c;
#pragma unroll
    for (int o = 1; o < 64; o <<= 1) {
        int a = __shfl_up(inc, o);
        if (lane >= o) inc += a;
    }
    if (lane == 63) wsum[wid] = inc;
    __syncthreads();
    int off = 0;
    for (int j = 0; j < wid; ++j) off += wsum[j];
    int excl = off + inc - c;
    gcnt[t] = c;
    goff[t] = excl;
    gcur[t] = excl;
}

// ---------------------------------------------------------------------------
// C: emit items {x,y,±wh,±wv} into exact per-bucket segments
// ---------------------------------------------------------------------------
__global__ __launch_bounds__(1024) void emit_kernel(
        const float4* __restrict__ recA, const float4* __restrict__ recB,
        int* __restrict__ gcur, float4* __restrict__ items) {
    __shared__ int lcnt[NBUCKET];
    __shared__ int lbase[NBUCKET];
    int tid = threadIdx.x;
    if (tid < NBUCKET) lcnt[tid] = 0;
    __syncthreads();
    int n = blockIdx.x * 1024 + tid;
    bool valid = n < NUM_NETS;
    float4 ra, rb;
    int kx1 = 0, kx2 = 0, ky1 = 0, ky2 = 0;
    if (valid) {
        ra = recA[n]; rb = recB[n];
        unsigned pkx = __float_as_uint(rb.z), pky = __float_as_uint(rb.w);
        kx1 = (int)(pkx & 0xffffu); kx2 = (int)(pkx >> 16);
        ky1 = (int)(pky & 0xffffu); ky2 = (int)(pky >> 16);
#pragma unroll
        for (int cx = 0; cx < 2; ++cx) {
            int kx = cx ? kx2 : kx1;
#pragma unroll
            for (int cy = 0; cy < 2; ++cy) {
                int ky = cy ? ky2 : ky1;
                for_each_bucket(kx, ky, [&](int b) { atomicAdd(&lcnt[b], 1); });
            }
        }
    }
    __syncthreads();
    if (tid < NBUCKET) {
        lbase[tid] = atomicAdd(&gcur[tid], lcnt[tid]);
        lcnt[tid] = 0;
    }
    __syncthreads();
    if (valid) {
        float xmn = ra.x, xmx = ra.y, ymn = ra.z, ymx = ra.w;
        float wh = rb.x, wv = rb.y;
#pragma unroll
        for (int cx = 0; cx < 2; ++cx) {
            int   kx = cx ? kx2 : kx1;
            float xc = cx ? xmx : xmn;
#pragma unroll
            for (int cy = 0; cy < 2; ++cy) {
                int   ky = cy ? ky2 : ky1;
                float yc = cy ? ymx : ymn;
                float sg = (cx ^ cy) ? -1.0f : 1.0f;
                float4 item = make_float4(xc, yc, sg * wh, sg * wv);
                for_each_bucket(kx, ky, [&](int b) {
                    int rank = atomicAdd(&lcnt[b], 1);
                    int pos  = lbase[b] + rank;
                    if (pos < ITEMS_MAX) items[pos] = item;
                });
            }
        }
    }
}

// ---------------------------------------------------------------------------
// D: per-bucket accumulate with NATIVE INT LDS atomics (fixed-point 2^21).
// fp32 LDS atomicAdd lowers to a CAS loop on gfx950 (R11 ablation: 50us with
// zero global reads); integer ds_add is native and fast (bbox/emit evidence).
// ---------------------------------------------------------------------------
__global__ __launch_bounds__(256) void accum_kernel(
        const float4* __restrict__ items,
        const int* __restrict__ gcnt, const int* __restrict__ goff,
        float* __restrict__ Uh, float* __restrict__ Uv) {
    __shared__ int accH[SW * SLH];      /* 2 KB, fixed-point */
    __shared__ int accV[SW * SLH];      /* 2 KB, fixed-point */
    int b  = blockIdx.x;
    int st = b >> 3, sl = b & 7;
    int x0 = st * SW, y0 = sl * SLH;
    int tid = threadIdx.x;
    for (int k = tid; k < SW * SLH; k += 256) { accH[k] = 0; accV[k] = 0; }
    __syncthreads();
    int i0  = goff[b];
    int end = min(i0 + gcnt[b], ITEMS_MAX);
    for (int q = i0 + tid; q < end; q += 256) {
        float4 it = items[q];
        int kx = min(NB - 1, (int)(it.x * INV_H));
        int ky = min(NB - 1, (int)(it.y * INV_H));
        float dx0 = (kx + 1) * BIN_H - it.x;
        float dx1 = it.x - kx * BIN_H;
        float dy0 = (ky + 1) * BIN_H - it.y;
        float dy1 = it.y - ky * BIN_H;
        int gy = ky - y0;
        bool ok0 = (unsigned)gy < (unsigned)SLH;
        bool ok1 = ((unsigned)(gy + 1) < (unsigned)SLH) && (ky + 1 < NB);
        int c = kx - x0;
#pragma unroll
        for (int cc = 0; cc < 2; ++cc) {
            int col = c + cc;
            if ((unsigned)col < SW) {
                float dx = cc ? dx1 : dx0;
                if (ok0) {
                    int i = col * SLH + gy;
                    atomicAdd(&accH[i], __float2int_rn(it.z * dx * dy0 * FXS));
                    atomicAdd(&accV[i], __float2int_rn(it.w * dx * dy0 * FXS));
                }
                if (ok1) {
                    int i = col * SLH + gy + 1;
                    atomicAdd(&accH[i], __float2int_rn(it.z * dx * dy1 * FXS));
                    atomicAdd(&accV[i], __float2int_rn(it.w * dx * dy1 * FXS));
                }
            }
        }
    }
    __syncthreads();
    for (int k = tid; k < SW * SLH; k += 256) {
        int col = k >> 6, y = k & (SLH - 1);
        int gi = (x0 + col) * NB + y0 + y;
        Uh[gi] = (float)accH[k] * INV_FXS;
        Uv[gi] = (float)accV[k] * INV_FXS;
    }
}

// ---------------------------------------------------------------------------
// E: inclusive y-scan per grid-row (shuffle). 512 blocks x 512 thr.
// ---------------------------------------------------------------------------
__global__ void rowscan_kernel(float* __restrict__ Uh, float* __restrict__ Uv) {
    __shared__ float swh[8], swv[8];
    int x = blockIdx.x, tid = threadIdx.x;
    int lane = tid & 63, wid = tid >> 6;
    float h = Uh[x * NB + tid];
    float v = Uv[x * NB + tid];
#pragma unroll
    for (int o = 1; o < 64; o <<= 1) {
        float a = __shfl_up(h, o);
        float b = __shfl_up(v, o);
        if (lane >= o) { h += a; v += b; }
    }
    if (lane == 63) { swh[wid] = h; swv[wid] = v; }
    __syncthreads();
    float oh = 0.f, ov = 0.f;
    for (int j = 0; j < wid; ++j) { oh += swh[j]; ov += swv[j]; }
    Uh[x * NB + tid] = h + oh;
    Uv[x * NB + tid] = v + ov;
}

// ---------------------------------------------------------------------------
// F: per-stripe partial column scans + totals
// ---------------------------------------------------------------------------
__global__ void colscan_partial_kernel(float* __restrict__ Uh,
                                       float* __restrict__ Uv,
                                       float* __restrict__ totH,
                                       float* __restrict__ totV) {
    int s = blockIdx.x;
    int t = blockIdx.y * blockDim.x + threadIdx.x;
    float h = 0.f, v = 0.f;
#pragma unroll
    for (int i = 0; i < STRIPE; ++i) {
        int row = s * STRIPE + i;
        h += Uh[row * NB + t];  Uh[row * NB + t] = h;
        v += Uv[row * NB + t];  Uv[row * NB + t] = v;
    }
    totH[s * NB + t] = h;
    totV[s * NB + t] = v;
}

// ---------------------------------------------------------------------------
// G: stripe offsets + fused epilogue
// ---------------------------------------------------------------------------
__global__ void colscan_finish_kernel(const float* __restrict__ Uh,
                                      const float* __restrict__ Uv,
                                      const float* __restrict__ totH,
                                      const float* __restrict__ totV,
                                      float* __restrict__ out) {
    int s = blockIdx.x;
    int t = blockIdx.y * blockDim.x + threadIdx.x;
    float offh = 0.f, offv = 0.f;
    for (int s2 = 0; s2 < s; ++s2) {
        offh += totH[s2 * NB + t];
        offv += totV[s2 * NB + t];
    }
#pragma unroll
    for (int i = 0; i < STRIPE; ++i) {
        int row = s * STRIPE + i;
        float h = fabsf(Uh[row * NB + t] + offh) * OUT_SCALE;
        float v = fabsf(Uv[row * NB + t] + offv) * OUT_SCALE;
        float m = fmaxf(h, v);
        out[row * NB + t] = fminf(fmaxf(m * m, 0.5f), 2.0f);
    }
}

// ---------------------------------------------------------------------------
// Fallback (tiny workspace): global-atomic scatter + scans
// ---------------------------------------------------------------------------
__global__ void scatter_kernel(const float* __restrict__ pin_pos,
                               const int*   __restrict__ flat_netpin,
                               const float* __restrict__ net_weights,
                               float* __restrict__ Uh,
                               float* __restrict__ Uv) {
    int n = blockIdx.x * blockDim.x + threadIdx.x;
    if (n >= NUM_NETS) return;
    float xmn = 1e30f, xmx = -1e30f, ymn = 1e30f, ymx = -1e30f;
#pragma unroll
    for (int p = 0; p < PINS_PER_NET; ++p) {
        int pi  = flat_netpin[n * PINS_PER_NET + p];
        float x = pin_pos[pi];
        float y = pin_pos[NUM_PINS + pi];
        xmn = fminf(xmn, x); xmx = fmaxf(xmx, x);
        ymn = fminf(ymn, y); ymx = fmaxf(ymx, y);
    }
    float w  = net_weights[n];
    float wh = w / (ymx - ymn), wv = w / (xmx - xmn);
    int kx1 = min(NB - 1, (int)(xmn * INV_H));
    int kx2 = min(NB - 1, (int)(xmx * INV_H));
    int ky1 = min(NB - 1, (int)(ymn * INV_H));
    int ky2 = min(NB - 1, (int)(ymx * INV_H));
    int   xi[4] = { kx1, kx1 + 1, kx2, kx2 + 1 };
    float xv[4] = { (kx1 + 1) * BIN_H - xmn,  xmn - kx1 * BIN_H,
                    xmx - (kx2 + 1) * BIN_H,  kx2 * BIN_H - xmx };
    int   yi[4] = { ky1, ky1 + 1, ky2, ky2 + 1 };
    float yv[4] = { (ky1 + 1) * BIN_H - ymn,  ymn - ky1 * BIN_H,
                    ymx - (ky2 + 1) * BIN_H,  ky2 * BIN_H - ymx };
#pragma unroll
    for (int a = 0; a < 4; ++a) {
        if (xi[a] >= NB) continue;
#pragma unroll
        for (int b2 = 0; b2 < 4; ++b2) {
            if (yi[b2] >= NB) continue;
            float prod = xv[a] * yv[b2];
            atomicAdd(&Uh[xi[a] * NB + yi[b2]], wh * prod);
            atomicAdd(&Uv[xi[a] * NB + yi[b2]], wv * prod);
        }
    }
}

__global__ void fb_rowscan_kernel(float* __restrict__ Uh, float* __restrict__ Uv) {
    __shared__ float sh[NB];
    __shared__ float sv[NB];
    int rr = blockIdx.x, t = threadIdx.x;
    sh[t] = Uh[rr * NB + t];
    sv[t] = Uv[rr * NB + t];
    __syncthreads();
#pragma unroll
    for (int off = 1; off < NB; off <<= 1) {
        float a = (t >= off) ? sh[t - off] : 0.0f;
        float b = (t >= off) ? sv[t - off] : 0.0f;
        __syncthreads();
        sh[t] += a; sv[t] += b;
        __syncthreads();
    }
    Uh[rr * NB + t] = sh[t];
    Uv[rr * NB + t] = sv[t];
}

__global__ void fb_colscan_kernel(const float* __restrict__ Uh,
                                  const float* __restrict__ Uv,
                                  float* __restrict__ out) {
    int t = blockIdx.x * blockDim.x + threadIdx.x;
    if (t >= NB) return;
    float sh = 0.f, sv = 0.f;
    for (int i = 0; i < NB; ++i) {
        sh += Uh[i * NB + t];
        sv += Uv[i * NB + t];
        float h = fabsf(sh) * OUT_SCALE;
        float v = fabsf(sv) * OUT_SCALE;
        float m = fmaxf(h, v);
        out[i * NB + t] = fminf(fmaxf(m * m, 0.5f), 2.0f);
    }
}

extern "C" void kernel_launch(void* const* d_in, const int* in_sizes, int n_in,
                              void* d_out, int out_size, void* d_ws, size_t ws_size,
                              hipStream_t stream) {
    const float* pin_pos     = (const float*)d_in[0];
    const int*   flat_netpin = (const int*)d_in[2];
    const float* net_weights = (const float*)d_in[3];
    float* out = (float*)d_out;
    float* ws  = (float*)d_ws;

    const size_t o_recA = 0;
    const size_t o_recB = o_recA + (size_t)NUM_NETS * 4;
    const size_t o_pcnt = o_recB + (size_t)NUM_NETS * 4;
    const size_t o_gcnt = o_pcnt + (size_t)NBLK * NBUCKET;
    const size_t o_goff = o_gcnt + NBUCKET;
    const size_t o_gcur = o_goff + NBUCKET;
    const size_t o_itm  = (o_gcur + NBUCKET + 3) & ~(size_t)3;
    const size_t o_Uh   = o_itm + (size_t)ITEMS_MAX * 4;
    const size_t o_Uv   = o_Uh + (size_t)NB * NB;
    const size_t o_Th   = o_Uv + (size_t)NB * NB;
    const size_t o_Tv   = o_Th + (size_t)NSTRIPE * NB;
    const size_t need   = o_Tv + (size_t)NSTRIPE * NB;

    if (ws_size < need * sizeof(float)) {
        float* Uh = ws;
        float* Uv = ws + (size_t)NB * NB;
        hipMemsetAsync(ws, 0, 2 * (size_t)NB * NB * sizeof(float), stream);
        scatter_kernel<<<(NUM_NETS + 255) / 256, 256, 0, stream>>>(
            pin_pos, flat_netpin, net_weights, Uh, Uv);
        fb_rowscan_kernel<<<NB, NB, 0, stream>>>(Uh, Uv);
        fb_colscan_kernel<<<2, 256, 0, stream>>>(Uh, Uv, out);
        return;
    }

    float4* recA  = (float4*)(ws + o_recA);
    float4* recB  = (float4*)(ws + o_recB);
    int*    pcnt  = (int*)(ws + o_pcnt);
    int*    gcnt  = (int*)(ws + o_gcnt);
    int*    goff  = (int*)(ws + o_goff);
    int*    gcur  = (int*)(ws + o_gcur);
    float4* items = (float4*)(ws + o_itm);
    float*  Uh    = ws + o_Uh;
    float*  Uv    = ws + o_Uv;
    float*  Th    = ws + o_Th;
    float*  Tv    = ws + o_Tv;

    bbox_count_kernel<<<NBLK, 1024, 0, stream>>>(
        pin_pos, flat_netpin, net_weights, recA, recB, pcnt);

    offsets_kernel<<<1, 512, 0, stream>>>(pcnt, gcnt, goff, gcur);

    emit_kernel<<<NBLK, 1024, 0, stream>>>(recA, recB, gcur, items);

    accum_kernel<<<NBUCKET, 256, 0, stream>>>(items, gcnt, goff, Uh, Uv);

    rowscan_kernel<<<NB, NB, 0, stream>>>(Uh, Uv);

    colscan_partial_kernel<<<dim3(NSTRIPE, 4), 128, 0, stream>>>(Uh, Uv, Th, Tv);

    colscan_finish_kernel<<<dim3(NSTRIPE, 4), 128, 0, stream>>>(Uh, Uv, Th, Tv, out);
}

// Round 13
// 57.338 us; speedup vs baseline: 8.1264x; 1.1873x over previous
//
#include <hip/hip_runtime.h>

#define NUM_NETS     100000
#define PINS_PER_NET 5
#define NUM_PINS     (NUM_NETS * PINS_PER_NET)
#define NB           512
#define BIN_H        1.953125f          /* 1000/512, exact in fp32 */
#define INV_H        0.512f             /* 512/1000 */
#define OUT_SCALE    (1.0f / 195.3125f) /* 1/(BIN_SIZE_X * 100 tracks) */

#define SW           8                  /* stripe width (x bins) */
#define NSTRIPES     (NB / SW)          /* 64 */
#define CAP          24576              /* items per stripe bucket (worst ~16K) */

#define FXS          2097152.0f         /* 2^21 fixed-point scale */
#define INV_FXS      (1.0f / 2097152.0f)

// ---------------------------------------------------------------------------
// K_A: bbox + emit 16B items {x, y, s*wh, s*wv} into per-stripe buckets.
// (R6-verified fast path: block LDS counts -> one global atomic/stripe/block)
// ---------------------------------------------------------------------------
__global__ __launch_bounds__(256) void bbox_emit_kernel(
        const float* __restrict__ pin_pos,
        const int*   __restrict__ flat_netpin,
        const float* __restrict__ net_weights,
        int* __restrict__ gcur,
        float4* __restrict__ bucket) {
    __shared__ int lcnt[NSTRIPES];
    __shared__ int lbase[NSTRIPES];
    int tid = threadIdx.x;
    if (tid < NSTRIPES) lcnt[tid] = 0;
    __syncthreads();

    int n = blockIdx.x * 256 + tid;
    bool valid = n < NUM_NETS;
    float xmn = 1e30f, xmx = -1e30f, ymn = 1e30f, ymx = -1e30f;
    float wh = 0.f, wv = 0.f;
    int kx1 = 0, kx2 = 0;
    if (valid) {
#pragma unroll
        for (int p = 0; p < PINS_PER_NET; ++p) {
            int pi  = flat_netpin[n * PINS_PER_NET + p];
            float x = pin_pos[pi];
            float y = pin_pos[NUM_PINS + pi];
            xmn = fminf(xmn, x); xmx = fmaxf(xmx, x);
            ymn = fminf(ymn, y); ymx = fmaxf(ymx, y);
        }
        float w = net_weights[n];
        wh = w / (ymx - ymn);
        wv = w / (xmx - xmn);
        kx1 = min(NB - 1, (int)(xmn * INV_H));
        kx2 = min(NB - 1, (int)(xmx * INV_H));
#pragma unroll
        for (int cx = 0; cx < 2; ++cx) {
            int kx = cx ? kx2 : kx1;
            int s0 = kx >> 3;
            atomicAdd(&lcnt[s0], 2);
            if (kx + 1 < NB && ((kx + 1) >> 3) != s0)
                atomicAdd(&lcnt[(kx + 1) >> 3], 2);
        }
    }
    __syncthreads();
    if (tid < NSTRIPES) {
        lbase[tid] = atomicAdd(&gcur[tid], lcnt[tid]);
        lcnt[tid] = 0;
    }
    __syncthreads();
    if (valid) {
#pragma unroll
        for (int cx = 0; cx < 2; ++cx) {
            int   kx = cx ? kx2 : kx1;
            float xc = cx ? xmx : xmn;
            int s0 = kx >> 3;
            int s1 = (kx + 1 < NB) ? ((kx + 1) >> 3) : s0;
#pragma unroll
            for (int cy = 0; cy < 2; ++cy) {
                float yc = cy ? ymx : ymn;
                float sg = ((cx ^ cy) ? -1.0f : 1.0f);
                float4 item = make_float4(xc, yc, sg * wh, sg * wv);
                {
                    int rank = atomicAdd(&lcnt[s0], 1);
                    int pos  = lbase[s0] + rank;
                    if (pos < CAP) bucket[(size_t)s0 * CAP + pos] = item;
                }
                if (s1 != s0) {
                    int rank = atomicAdd(&lcnt[s1], 1);
                    int pos  = lbase[s1] + rank;
                    if (pos < CAP) bucket[(size_t)s1 * CAP + pos] = item;
                }
            }
        }
    }
}

// ---------------------------------------------------------------------------
// K_B: one block per stripe. INT fixed-point accumulate (native ds_add) ->
// convert to float in LDS -> shuffle y-scan (conflict-free) -> x-partial
// scan + totals -> dump. 64 blocks x 1024 threads, 32KB LDS.
// ---------------------------------------------------------------------------
__global__ __launch_bounds__(1024) void stripe_kernel(
        const float4* __restrict__ bucket,
        const int* __restrict__ gcur,
        float* __restrict__ UpH, float* __restrict__ UpV,
        float* __restrict__ Th,  float* __restrict__ Tv) {
    __shared__ int   acc[2 * SW * NB];          /* 32 KB: H then V */
    __shared__ float wsc[32];                   /* wave-scan partials */
    int st  = blockIdx.x;
    int tid = threadIdx.x;
    int x0  = st * SW;
    int* accH = acc;
    int* accV = acc + SW * NB;

    for (int k = tid; k < 2 * SW * NB; k += 1024) acc[k] = 0;
    __syncthreads();

    /* ---- accumulate (int fixed-point, native LDS atomics) ---- */
    int cnt = min(gcur[st], CAP);
    const float4* bk = bucket + (size_t)st * CAP;
    for (int q = tid; q < cnt; q += 1024) {
        float4 it = bk[q];
        int kx = min(NB - 1, (int)(it.x * INV_H));
        int ky = min(NB - 1, (int)(it.y * INV_H));
        float dx0 = (kx + 1) * BIN_H - it.x;
        float dx1 = it.x - kx * BIN_H;
        float dy0 = (ky + 1) * BIN_H - it.y;
        float dy1 = it.y - ky * BIN_H;
        bool y1ok = (ky + 1) < NB;
        int c = kx - x0;
#pragma unroll
        for (int cc = 0; cc < 2; ++cc) {
            int col = c + cc;
            if ((unsigned)col < SW) {
                float dx = cc ? dx1 : dx0;
                int b = col * NB + ky;
                atomicAdd(&accH[b], __float2int_rn(it.z * dx * dy0 * FXS));
                atomicAdd(&accV[b], __float2int_rn(it.w * dx * dy0 * FXS));
                if (y1ok) {
                    atomicAdd(&accH[b + 1], __float2int_rn(it.z * dx * dy1 * FXS));
                    atomicAdd(&accV[b + 1], __float2int_rn(it.w * dx * dy1 * FXS));
                }
            }
        }
    }
    __syncthreads();

    /* ---- convert int -> float in place ---- */
    float* fH = (float*)accH;
    float* fV = (float*)accV;
    for (int k = tid; k < 2 * SW * NB; k += 1024)
        ((float*)acc)[k] = (float)acc[k] * INV_FXS;
    __syncthreads();

    /* ---- y-scan: 8 rows x 512, two rows per pass, shuffle-based ---- */
    int half = tid >> 9;           /* 0 or 1: which row of the pair */
    int y    = tid & 511;
    int lane = tid & 63;
    int wv16 = tid >> 6;           /* wave index 0..15 */
    int wrow0 = half * 8;          /* first wave of this row's 8 waves */
#pragma unroll
    for (int rp = 0; rp < 4; ++rp) {
        int row = rp * 2 + half;
        float vH = fH[row * NB + y];
        float vV = fV[row * NB + y];
#pragma unroll
        for (int o = 1; o < 64; o <<= 1) {
            float a = __shfl_up(vH, o);
            float b = __shfl_up(vV, o);
            if (lane >= o) { vH += a; vV += b; }
        }
        if (lane == 63) { wsc[wv16] = vH; wsc[16 + wv16] = vV; }
        __syncthreads();
        float oh = 0.f, ov = 0.f;
        for (int j = wrow0; j < wv16; ++j) { oh += wsc[j]; ov += wsc[16 + j]; }
        fH[row * NB + y] = vH + oh;
        fV[row * NB + y] = vV + ov;
        __syncthreads();
    }

    /* ---- x-partial scan over the 8 rows + totals ---- */
    if (tid < NB) {
        float f = 0.f;
#pragma unroll
        for (int rr = 0; rr < SW; ++rr) {
            int i = rr * NB + tid;
            f += fH[i]; fH[i] = f;
        }
        Th[st * NB + tid] = f;
    } else {
        int yy = tid - NB;
        float f = 0.f;
#pragma unroll
        for (int rr = 0; rr < SW; ++rr) {
            int i = rr * NB + yy;
            f += fV[i]; fV[i] = f;
        }
        Tv[st * NB + yy] = f;
    }
    __syncthreads();

    /* ---- dump scanned partials, coalesced ---- */
    for (int k = tid; k < SW * NB; k += 1024) {
        int rr = k >> 9, yy = k & (NB - 1);
        int gi = (x0 + rr) * NB + yy;
        UpH[gi] = fH[k];
        UpV[gi] = fV[k];
    }
}

// ---------------------------------------------------------------------------
// K_C: cross-stripe exclusive offsets + fused epilogue.
// ---------------------------------------------------------------------------
__global__ __launch_bounds__(512) void finish_kernel(
        const float* __restrict__ UpH, const float* __restrict__ UpV,
        const float* __restrict__ Th,  const float* __restrict__ Tv,
        float* __restrict__ out) {
    int st = blockIdx.x;
    int y  = threadIdx.x;
    float offh = 0.f, offv = 0.f;
    for (int s2 = 0; s2 < st; ++s2) {
        offh += Th[s2 * NB + y];
        offv += Tv[s2 * NB + y];
    }
#pragma unroll
    for (int rr = 0; rr < SW; ++rr) {
        int i = (st * SW + rr) * NB + y;
        float h = fabsf(UpH[i] + offh) * OUT_SCALE;
        float v = fabsf(UpV[i] + offv) * OUT_SCALE;
        float m = fmaxf(h, v);
        out[i] = fminf(fmaxf(m * m, 0.5f), 2.0f);
    }
}

// ---------------------------------------------------------------------------
// Fallback (tiny workspace): global-atomic scatter + scans
// ---------------------------------------------------------------------------
__global__ void scatter_kernel(const float* __restrict__ pin_pos,
                               const int*   __restrict__ flat_netpin,
                               const float* __restrict__ net_weights,
                               float* __restrict__ Uh,
                               float* __restrict__ Uv) {
    int n = blockIdx.x * blockDim.x + threadIdx.x;
    if (n >= NUM_NETS) return;
    float xmn = 1e30f, xmx = -1e30f, ymn = 1e30f, ymx = -1e30f;
#pragma unroll
    for (int p = 0; p < PINS_PER_NET; ++p) {
        int pi  = flat_netpin[n * PINS_PER_NET + p];
        float x = pin_pos[pi];
        float y = pin_pos[NUM_PINS + pi];
        xmn = fminf(xmn, x); xmx = fmaxf(xmx, x);
        ymn = fminf(ymn, y); ymx = fmaxf(ymx, y);
    }
    float w  = net_weights[n];
    float wh = w / (ymx - ymn), wv = w / (xmx - xmn);
    int kx1 = min(NB - 1, (int)(xmn * INV_H));
    int kx2 = min(NB - 1, (int)(xmx * INV_H));
    int ky1 = min(NB - 1, (int)(ymn * INV_H));
    int ky2 = min(NB - 1, (int)(ymx * INV_H));
    int   xi[4] = { kx1, kx1 + 1, kx2, kx2 + 1 };
    float xv[4] = { (kx1 + 1) * BIN_H - xmn,  xmn - kx1 * BIN_H,
                    xmx - (kx2 + 1) * BIN_H,  kx2 * BIN_H - xmx };
    int   yi[4] = { ky1, ky1 + 1, ky2, ky2 + 1 };
    float yv[4] = { (ky1 + 1) * BIN_H - ymn,  ymn - ky1 * BIN_H,
                    ymx - (ky2 + 1) * BIN_H,  ky2 * BIN_H - ymx };
#pragma unroll
    for (int a = 0; a < 4; ++a) {
        if (xi[a] >= NB) continue;
#pragma unroll
        for (int b2 = 0; b2 < 4; ++b2) {
            if (yi[b2] >= NB) continue;
            float prod = xv[a] * yv[b2];
            atomicAdd(&Uh[xi[a] * NB + yi[b2]], wh * prod);
            atomicAdd(&Uv[xi[a] * NB + yi[b2]], wv * prod);
        }
    }
}

__global__ void fb_rowscan_kernel(float* __restrict__ Uh, float* __restrict__ Uv) {
    __shared__ float sh[NB];
    __shared__ float sv[NB];
    int rr = blockIdx.x, t = threadIdx.x;
    sh[t] = Uh[rr * NB + t];
    sv[t] = Uv[rr * NB + t];
    __syncthreads();
#pragma unroll
    for (int off = 1; off < NB; off <<= 1) {
        float a = (t >= off) ? sh[t - off] : 0.0f;
        float b = (t >= off) ? sv[t - off] : 0.0f;
        __syncthreads();
        sh[t] += a; sv[t] += b;
        __syncthreads();
    }
    Uh[rr * NB + t] = sh[t];
    Uv[rr * NB + t] = sv[t];
}

__global__ void fb_colscan_kernel(const float* __restrict__ Uh,
                                  const float* __restrict__ Uv,
                                  float* __restrict__ out) {
    int t = blockIdx.x * blockDim.x + threadIdx.x;
    if (t >= NB) return;
    float sh = 0.f, sv = 0.f;
    for (int i = 0; i < NB; ++i) {
        sh += Uh[i * NB + t];
        sv += Uv[i * NB + t];
        float h = fabsf(sh) * OUT_SCALE;
        float v = fabsf(sv) * OUT_SCALE;
        float m = fmaxf(h, v);
        out[i * NB + t] = fminf(fmaxf(m * m, 0.5f), 2.0f);
    }
}

extern "C" void kernel_launch(void* const* d_in, const int* in_sizes, int n_in,
                              void* d_out, int out_size, void* d_ws, size_t ws_size,
                              hipStream_t stream) {
    const float* pin_pos     = (const float*)d_in[0];
    const int*   flat_netpin = (const int*)d_in[2];
    const float* net_weights = (const float*)d_in[3];
    float* out = (float*)d_out;
    float* ws  = (float*)d_ws;

    /* layout (floats): gcur[64] | bucket[64*CAP*4] | Th[64*512] | Tv[64*512]
                        | UpH[512*512] | UpV[512*512]            (~27.6 MB) */
    const size_t o_cur = 0;
    const size_t o_bkt = 64;
    const size_t o_Th  = o_bkt + (size_t)NSTRIPES * CAP * 4;
    const size_t o_Tv  = o_Th + (size_t)NSTRIPES * NB;
    const size_t o_UpH = o_Tv + (size_t)NSTRIPES * NB;
    const size_t o_UpV = o_UpH + (size_t)NB * NB;
    const size_t need  = o_UpV + (size_t)NB * NB;

    if (ws_size < need * sizeof(float)) {
        float* Uh = ws;
        float* Uv = ws + (size_t)NB * NB;
        hipMemsetAsync(ws, 0, 2 * (size_t)NB * NB * sizeof(float), stream);
        scatter_kernel<<<(NUM_NETS + 255) / 256, 256, 0, stream>>>(
            pin_pos, flat_netpin, net_weights, Uh, Uv);
        fb_rowscan_kernel<<<NB, NB, 0, stream>>>(Uh, Uv);
        fb_colscan_kernel<<<2, 256, 0, stream>>>(Uh, Uv, out);
        return;
    }

    int*    gcur   = (int*)(ws + o_cur);
    float4* bucket = (float4*)(ws + o_bkt);
    float*  Th     = ws + o_Th;
    float*  Tv     = ws + o_Tv;
    float*  UpH    = ws + o_UpH;
    float*  UpV    = ws + o_UpV;

    hipMemsetAsync(gcur, 0, NSTRIPES * sizeof(int), stream);

    bbox_emit_kernel<<<(NUM_NETS + 255) / 256, 256, 0, stream>>>(
        pin_pos, flat_netpin, net_weights, gcur, bucket);

    stripe_kernel<<<NSTRIPES, 1024, 0, stream>>>(bucket, gcur, UpH, UpV, Th, Tv);

    finish_kernel<<<NSTRIPES, 512, 0, stream>>>(UpH, UpV, Th, Tv, out);
}